// Round 1
// baseline (436.652 us; speedup 1.0000x reference)
//
#include <hip/hip_runtime.h>
#include <stdint.h>

typedef uint16_t u16;
typedef __attribute__((ext_vector_type(4))) float f32x4;
typedef __attribute__((ext_vector_type(4))) unsigned short u16x4;
typedef __attribute__((ext_vector_type(8))) short s16x8;
typedef __attribute__((ext_vector_type(8))) __bf16 bf16x8;

#define HIDDEN 2048
#define LSEQ   2048
#define NH     16
#define HD     128
#define NQK    6144   // 3*HIDDEN, qkv row stride

// ---------- bf16 helpers (RNE) ----------
__device__ __forceinline__ u16 f2b(float f) {
  union { float f; uint32_t u; } v; v.f = f;
  uint32_t r = v.u + 0x7fffu + ((v.u >> 16) & 1u);
  return (u16)(r >> 16);
}
__device__ __forceinline__ float b2f(u16 h) {
  union { uint32_t u; float f; } v; v.u = ((uint32_t)h) << 16;
  return v.f;
}

__device__ __forceinline__ void gload16(const void* g, void* l) {
  __builtin_amdgcn_global_load_lds((const __attribute__((address_space(1))) void*)g,
                                   (__attribute__((address_space(3))) void*)l, 16, 0, 0);
}
__device__ __forceinline__ f32x4 mfma16(bf16x8 a, bf16x8 b, f32x4 c) {
  return __builtin_amdgcn_mfma_f32_16x16x32_bf16(a, b, c, 0, 0, 0);
}

// ---------- f32 -> bf16 bulk convert ----------
__global__ void k_f32_to_bf16(const float* __restrict__ in, u16* __restrict__ out, int n4) {
  int i = blockIdx.x * 256 + threadIdx.x;
  if (i >= n4) return;
  float4 v = ((const float4*)in)[i];
  u16x4 o = { f2b(v.x), f2b(v.y), f2b(v.z), f2b(v.w) };
  ((u16x4*)out)[i] = o;
}

// ---------- transpose + convert: W[R][C] f32 -> WT[C][R] bf16 ----------
__global__ __launch_bounds__(256) void k_transpose_bf16(const float* __restrict__ W,
                                                        u16* __restrict__ WT, int R, int C) {
  __shared__ u16 tile[64][65];
  const int bx = blockIdx.x, by = blockIdx.y;   // bx: col tile, by: row tile
  const int t = threadIdx.x;
  const int g = t >> 4, k = t & 15;
#pragma unroll
  for (int p = 0; p < 4; ++p) {
    int r = by * 64 + p * 16 + g;
    int c = bx * 64 + k * 4;
    float4 v = *(const float4*)(W + (size_t)r * C + c);
    tile[p * 16 + g][k * 4 + 0] = f2b(v.x);
    tile[p * 16 + g][k * 4 + 1] = f2b(v.y);
    tile[p * 16 + g][k * 4 + 2] = f2b(v.z);
    tile[p * 16 + g][k * 4 + 3] = f2b(v.w);
  }
  __syncthreads();
#pragma unroll
  for (int p = 0; p < 4; ++p) {
    int n = bx * 64 + p * 16 + g;
    int kk = by * 64 + k * 4;
    u16x4 o = { tile[k * 4 + 0][p * 16 + g], tile[k * 4 + 1][p * 16 + g],
                tile[k * 4 + 2][p * 16 + g], tile[k * 4 + 3][p * 16 + g] };
    *(u16x4*)(WT + (size_t)n * R + kk) = o;
  }
}

// ---------- RoPE cos/sin table: tab[l][j] = {cos,sin}(pos[l]*10000^{-j/64}) ----------
__global__ void k_rope_table(const int* __restrict__ pos, float* __restrict__ tab, int pstride) {
  int i = blockIdx.x * 256 + threadIdx.x;   // l*64 + j
  int l = i >> 6, j = i & 63;
  float p = (float)pos[(size_t)l * pstride];
  float th = p * expf(-(float)j * 0.14391156642178528f);  // ln(10000)/64
  tab[2 * i + 0] = cosf(th);
  tab[2 * i + 1] = sinf(th);
}

// ---------- RoPE apply (faithful repeat_interleave + rotate_half mix) ----------
__global__ void k_rope_apply(u16* __restrict__ qkv, const float* __restrict__ tab) {
  int i = blockIdx.x * 256 + threadIdx.x;   // rows(4096) x mat(2) x h(16) x dp(64)
  int dp = i & 63;
  int h = (i >> 6) & 15;
  int mat = (i >> 10) & 1;
  int row = i >> 11;
  int l = row & (LSEQ - 1);
  const float* t1 = tab + 2 * (l * 64 + (dp >> 1));        // for out[dp]
  const float* t2 = tab + 2 * (l * 64 + 32 + (dp >> 1));   // for out[dp+64]
  size_t base = (size_t)row * NQK + mat * HIDDEN + h * HD + dp;
  float x1 = b2f(qkv[base]), x2 = b2f(qkv[base + 64]);
  qkv[base]      = f2b(t1[0] * x1 - t1[1] * x2);
  qkv[base + 64] = f2b(t2[0] * x2 + t2[1] * x1);
}

// ---------- bf16 GEMM, C = A[M][K] * Bt[N][K]^T, m97-style 128x128x32 ----------
template<int BF16OUT>
__global__ __launch_bounds__(256) void k_gemm(const u16* __restrict__ A, const u16* __restrict__ Bt,
                                              void* __restrict__ Cv, int M, int N, int K) {
  __shared__ __align__(16) u16 As[128 * 32];
  __shared__ __align__(16) u16 Bs[128 * 32];
  const int tid = threadIdx.x;
  const int wid = tid >> 6, lane = tid & 63;
  const int l15 = lane & 15, l4 = lane >> 4;
  const int bn = blockIdx.x, bm = blockIdx.y;
  const int wm = wid >> 1, wn = wid & 1;
  const u16* Ag = A + (size_t)bm * 128 * K;
  const u16* Bg = Bt + (size_t)bn * 128 * K;
  char* AsC = (char*)As; char* BsC = (char*)Bs;
  f32x4 acc[4][4] = {};

  for (int k0 = 0; k0 < K; k0 += 32) {
    {
      int c = wid * 64 + lane;                       // chunk id, 16B each, 4/row
      gload16(Ag + (size_t)(c >> 2) * K + k0 + (c & 3) * 8, AsC + (wid * 64) * 16);
      gload16(Bg + (size_t)(c >> 2) * K + k0 + (c & 3) * 8, BsC + (wid * 64) * 16);
      c += 256;
      gload16(Ag + (size_t)(c >> 2) * K + k0 + (c & 3) * 8, AsC + (256 + wid * 64) * 16);
      gload16(Bg + (size_t)(c >> 2) * K + k0 + (c & 3) * 8, BsC + (256 + wid * 64) * 16);
    }
    __syncthreads();
    bf16x8 af[4], bfv[4];
#pragma unroll
    for (int mi = 0; mi < 4; ++mi)
      af[mi] = *(const bf16x8*)(As + (wm * 64 + mi * 16 + l15) * 32 + l4 * 8);
#pragma unroll
    for (int nj = 0; nj < 4; ++nj)
      bfv[nj] = *(const bf16x8*)(Bs + (wn * 64 + nj * 16 + l15) * 32 + l4 * 8);
#pragma unroll
    for (int mi = 0; mi < 4; ++mi)
#pragma unroll
      for (int nj = 0; nj < 4; ++nj)
        acc[mi][nj] = mfma16(af[mi], bfv[nj], acc[mi][nj]);
    __syncthreads();
  }

#pragma unroll
  for (int mi = 0; mi < 4; ++mi) {
#pragma unroll
    for (int nj = 0; nj < 4; ++nj) {
      int row0 = bm * 128 + wm * 64 + mi * 16 + l4 * 4;
      int col  = bn * 128 + wn * 64 + nj * 16 + l15;
#pragma unroll
      for (int r = 0; r < 4; ++r) {
        float v = acc[mi][nj][r];
        if (BF16OUT) ((u16*)Cv)[(size_t)(row0 + r) * N + col] = f2b(v);
        else         ((float*)Cv)[(size_t)(row0 + r) * N + col] = v;
      }
    }
  }
}

// ---------- flash attention: 128 q-rows/block, 4 waves x 32 rows, KV tile 64 ----------
__global__ __launch_bounds__(256) void k_attn(const u16* __restrict__ qkv, u16* __restrict__ aout) {
  __shared__ __align__(16) u16 Ks[64 * 128];       // XOR-swizzled
  __shared__ __align__(16) u16 Vs[64 * 128];       // linear
  __shared__ __align__(16) u16 Ps[4 * 32 * 72];    // per-wave P, padded stride 72
  const int qt = blockIdx.x, h = blockIdx.y, b = blockIdx.z;
  const int tid = threadIdx.x, wid = tid >> 6, lane = tid & 63;
  const int l15 = lane & 15, l4 = lane >> 4;
  const float scale = 0.08838834764831845f;        // 1/sqrt(128)

  // Q fragments live in registers for the whole block
  bf16x8 qf[2][4];
#pragma unroll
  for (int mf = 0; mf < 2; ++mf) {
    int qrow = qt * 128 + wid * 32 + mf * 16 + l15;
    const u16* qp = qkv + (size_t)(b * LSEQ + qrow) * NQK + h * HD;
#pragma unroll
    for (int ks = 0; ks < 4; ++ks)
      qf[mf][ks] = *(const bf16x8*)(qp + ks * 32 + l4 * 8);
  }

  f32x4 acc_o[2][8] = {};
  float mrun[2][4], lrun[2][4];
#pragma unroll
  for (int mf = 0; mf < 2; ++mf)
#pragma unroll
    for (int r = 0; r < 4; ++r) { mrun[mf][r] = -1e30f; lrun[mf][r] = 0.f; }

  const u16* kb = qkv + (size_t)b * LSEQ * NQK + HIDDEN + h * HD;
  const u16* vb = qkv + (size_t)b * LSEQ * NQK + 2 * HIDDEN + h * HD;
  char* KsC = (char*)Ks;
  const int ntiles = 2 * qt + 2;                   // causal: kv tiles [0, 2qt+1]

  for (int t = 0; t < ntiles; ++t) {
    const int kv0 = t * 64;
    // stage K (pre-swizzled global source -> linear LDS) and V (linear)
#pragma unroll
    for (int p = 0; p < 4; ++p) {
      int c = p * 256 + tid;                       // 16 chunks of 16B per 128-elem row
      int row = c >> 4, sl = c & 15;
      gload16(kb + (size_t)(kv0 + row) * NQK + ((sl ^ (row & 7)) * 8), KsC + (p * 256 + wid * 64) * 16);
      gload16(vb + (size_t)(kv0 + row) * NQK + sl * 8, (char*)Vs + (p * 256 + wid * 64) * 16);
    }
    __syncthreads();

    // S = Q K^T
    f32x4 accs[2][4] = {};
#pragma unroll
    for (int ks = 0; ks < 4; ++ks) {
#pragma unroll
      for (int nj = 0; nj < 4; ++nj) {
        int row = nj * 16 + l15;
        int co = (ks * 64 + l4 * 16) ^ ((row & 7) << 4);
        bf16x8 kf = *(const bf16x8*)(KsC + row * 256 + co);
        accs[0][nj] = mfma16(qf[0][ks], kf, accs[0][nj]);
        accs[1][nj] = mfma16(qf[1][ks], kf, accs[1][nj]);
      }
    }

    // online softmax + P write
#pragma unroll
    for (int mf = 0; mf < 2; ++mf) {
      float pv[4][4];
      int qrow0 = qt * 128 + wid * 32 + mf * 16 + l4 * 4;
#pragma unroll
      for (int r = 0; r < 4; ++r) {
        float mx = -3e38f;
#pragma unroll
        for (int nj = 0; nj < 4; ++nj) {
          int kvcol = kv0 + nj * 16 + l15;
          float sv = (kvcol <= qrow0 + r) ? accs[mf][nj][r] * scale : -3e38f;
          pv[nj][r] = sv;
          mx = fmaxf(mx, sv);
        }
        mx = fmaxf(mx, __shfl_xor(mx, 1));
        mx = fmaxf(mx, __shfl_xor(mx, 2));
        mx = fmaxf(mx, __shfl_xor(mx, 4));
        mx = fmaxf(mx, __shfl_xor(mx, 8));
        float newm = fmaxf(mrun[mf][r], mx);
        float cf = __expf(mrun[mf][r] - newm);
        mrun[mf][r] = newm;
        float s = 0.f;
#pragma unroll
        for (int nj = 0; nj < 4; ++nj) {
          float e = __expf(pv[nj][r] - newm);
          pv[nj][r] = e;
          s += e;
        }
        s += __shfl_xor(s, 1);
        s += __shfl_xor(s, 2);
        s += __shfl_xor(s, 4);
        s += __shfl_xor(s, 8);
        lrun[mf][r] = lrun[mf][r] * cf + s;
#pragma unroll
        for (int df = 0; df < 8; ++df)
          acc_o[mf][df][r] *= cf;
      }
#pragma unroll
      for (int nj = 0; nj < 4; ++nj)
#pragma unroll
        for (int r = 0; r < 4; ++r)
          Ps[(wid * 32 + mf * 16 + l4 * 4 + r) * 72 + nj * 16 + l15] = f2b(pv[nj][r]);
    }
    __syncthreads();   // P visible; Ks reads done

    // O += P V
#pragma unroll
    for (int ks2 = 0; ks2 < 2; ++ks2) {
      bf16x8 pa[2];
#pragma unroll
      for (int mf = 0; mf < 2; ++mf)
        pa[mf] = *(const bf16x8*)(Ps + (wid * 32 + mf * 16 + l15) * 72 + ks2 * 32 + l4 * 8);
#pragma unroll
      for (int df = 0; df < 8; ++df) {
        s16x8 be;
#pragma unroll
        for (int j = 0; j < 8; ++j)
          be[j] = (short)Vs[(ks2 * 32 + l4 * 8 + j) * 128 + df * 16 + l15];
        bf16x8 bv = __builtin_bit_cast(bf16x8, be);
        acc_o[0][df] = mfma16(pa[0], bv, acc_o[0][df]);
        acc_o[1][df] = mfma16(pa[1], bv, acc_o[1][df]);
      }
    }
    __syncthreads();   // LDS consumed; safe to restage
  }

  // epilogue: O /= l, write bf16 [B*L][HIDDEN]
#pragma unroll
  for (int mf = 0; mf < 2; ++mf) {
    int qrow0 = qt * 128 + wid * 32 + mf * 16 + l4 * 4;
#pragma unroll
    for (int r = 0; r < 4; ++r) {
      float inv = 1.f / lrun[mf][r];
      u16* op = aout + (size_t)(b * LSEQ + qrow0 + r) * HIDDEN + h * HD;
#pragma unroll
      for (int df = 0; df < 8; ++df)
        op[df * 16 + l15] = f2b(acc_o[mf][df][r] * inv);
    }
  }
}

extern "C" void kernel_launch(void* const* d_in, const int* in_sizes, int n_in,
                              void* d_out, int out_size, void* d_ws, size_t ws_size,
                              hipStream_t stream) {
  const float* hidden = (const float*)d_in[0];
  // d_in[1] = attention_mask: causal, applied analytically in k_attn
  const int*   pos = (const int*)d_in[2];
  const float* Wq = (const float*)d_in[3];
  const float* Wk = (const float*)d_in[4];
  const float* Wv = (const float*)d_in[5];
  const float* Wo = (const float*)d_in[6];
  float* out = (float*)d_out;

  char* ws = (char*)d_ws;
  u16* hbf   = (u16*)ws;                                  // [4096][2048] bf16 (reused as attn_out)
  u16* WT    = (u16*)(ws + 16777216);                     // [6144][2048] bf16 = [WqT;WkT;WvT]
  u16* WoT   = (u16*)(ws + 16777216 + 25165824);          // [2048][2048] bf16
  u16* qkv   = (u16*)(ws + 50331648);                     // [4096][6144] bf16
  float* tab = (float*)(ws + 100663296);                  // [2048][64] {cos,sin}
  u16* aout  = hbf;

  int pstride = (in_sizes[2] == LSEQ) ? 1 : 2;            // int32 vs int64-as-int-pairs

  k_f32_to_bf16<<<8192, 256, 0, stream>>>(hidden, hbf, 2097152);
  dim3 tg(32, 32);
  k_transpose_bf16<<<tg, 256, 0, stream>>>(Wq, WT,                 2048, 2048);
  k_transpose_bf16<<<tg, 256, 0, stream>>>(Wk, WT + 2048 * 2048,   2048, 2048);
  k_transpose_bf16<<<tg, 256, 0, stream>>>(Wv, WT + 2 * 2048 * 2048, 2048, 2048);
  k_transpose_bf16<<<tg, 256, 0, stream>>>(Wo, WoT,                2048, 2048);
  k_rope_table<<<512, 256, 0, stream>>>(pos, tab, pstride);
  k_gemm<1><<<dim3(48, 32), 256, 0, stream>>>(hbf, WT, qkv, 4096, 6144, 2048);
  k_rope_apply<<<32768, 256, 0, stream>>>(qkv, tab);
  k_attn<<<dim3(16, 16, 2), 256, 0, stream>>>(qkv, aout);
  k_gemm<0><<<dim3(16, 32), 256, 0, stream>>>(aout, WoT, out, 4096, 2048, 2048);
}

// Round 2
// 371.246 us; speedup vs baseline: 1.1762x; 1.1762x over previous
//
#include <hip/hip_runtime.h>
#include <stdint.h>

typedef uint16_t u16;
typedef __attribute__((ext_vector_type(4))) float f32x4;
typedef __attribute__((ext_vector_type(2))) unsigned short u16x2;
typedef __attribute__((ext_vector_type(4))) unsigned short u16x4;
typedef __attribute__((ext_vector_type(8))) __bf16 bf16x8;

#define HIDDEN 2048
#define LSEQ   2048
#define NH     16
#define HD     128
#define NQK    6144   // 3*HIDDEN, qkv row stride

// ---------- bf16 helpers (RNE) ----------
__device__ __forceinline__ u16 f2b(float f) {
  union { float f; uint32_t u; } v; v.f = f;
  uint32_t r = v.u + 0x7fffu + ((v.u >> 16) & 1u);
  return (u16)(r >> 16);
}
__device__ __forceinline__ float b2f(u16 h) {
  union { uint32_t u; float f; } v; v.u = ((uint32_t)h) << 16;
  return v.f;
}

__device__ __forceinline__ void gload16(const void* g, void* l) {
  __builtin_amdgcn_global_load_lds((const __attribute__((address_space(1))) void*)g,
                                   (__attribute__((address_space(3))) void*)l, 16, 0, 0);
}
__device__ __forceinline__ f32x4 mfma16(bf16x8 a, bf16x8 b, f32x4 c) {
  return __builtin_amdgcn_mfma_f32_16x16x32_bf16(a, b, c, 0, 0, 0);
}

// ---------- f32 -> bf16 bulk convert ----------
__global__ void k_f32_to_bf16(const float* __restrict__ in, u16* __restrict__ out, int n4) {
  int i = blockIdx.x * 256 + threadIdx.x;
  if (i >= n4) return;
  float4 v = ((const float4*)in)[i];
  u16x4 o = { f2b(v.x), f2b(v.y), f2b(v.z), f2b(v.w) };
  ((u16x4*)out)[i] = o;
}

// ---------- transpose + convert: W[R][C] f32 -> WT[C][R] bf16 ----------
__global__ __launch_bounds__(256) void k_transpose_bf16(const float* __restrict__ W,
                                                        u16* __restrict__ WT, int R, int C) {
  __shared__ u16 tile[64][65];
  const int bx = blockIdx.x, by = blockIdx.y;
  const int t = threadIdx.x;
  const int g = t >> 4, k = t & 15;
#pragma unroll
  for (int p = 0; p < 4; ++p) {
    int r = by * 64 + p * 16 + g;
    int c = bx * 64 + k * 4;
    float4 v = *(const float4*)(W + (size_t)r * C + c);
    tile[p * 16 + g][k * 4 + 0] = f2b(v.x);
    tile[p * 16 + g][k * 4 + 1] = f2b(v.y);
    tile[p * 16 + g][k * 4 + 2] = f2b(v.z);
    tile[p * 16 + g][k * 4 + 3] = f2b(v.w);
  }
  __syncthreads();
#pragma unroll
  for (int p = 0; p < 4; ++p) {
    int n = bx * 64 + p * 16 + g;
    int kk = by * 64 + k * 4;
    u16x4 o = { tile[k * 4 + 0][p * 16 + g], tile[k * 4 + 1][p * 16 + g],
                tile[k * 4 + 2][p * 16 + g], tile[k * 4 + 3][p * 16 + g] };
    *(u16x4*)(WT + (size_t)n * R + kk) = o;
  }
}

// ---------- V transpose: qkv V part [b][l][h][d] -> vt[b][h][d][l] (bf16) ----------
__global__ __launch_bounds__(256) void k_transpose_v(const u16* __restrict__ qkv,
                                                     u16* __restrict__ vt) {
  __shared__ u16 tile[64][65];
  const int lt = blockIdx.x;        // l tile (64)
  const int dt = blockIdx.y;        // d tile (64)
  const int bh = blockIdx.z;        // b*16+h
  const int t = threadIdx.x;
  const int g = t >> 4, k = t & 15;
  const u16* src = qkv + (size_t)(bh >> 4) * LSEQ * NQK + 2 * HIDDEN + (bh & 15) * HD;
#pragma unroll
  for (int p = 0; p < 4; ++p) {
    int l = lt * 64 + p * 16 + g;
    int d = dt * 64 + k * 4;
    u16x4 v = *(const u16x4*)(src + (size_t)l * NQK + d);
    tile[p * 16 + g][k * 4 + 0] = v[0];
    tile[p * 16 + g][k * 4 + 1] = v[1];
    tile[p * 16 + g][k * 4 + 2] = v[2];
    tile[p * 16 + g][k * 4 + 3] = v[3];
  }
  __syncthreads();
  u16* dst = vt + (size_t)bh * HD * LSEQ;
#pragma unroll
  for (int p = 0; p < 4; ++p) {
    int d = dt * 64 + p * 16 + g;
    int l = lt * 64 + k * 4;
    u16x4 o = { tile[k * 4 + 0][p * 16 + g], tile[k * 4 + 1][p * 16 + g],
                tile[k * 4 + 2][p * 16 + g], tile[k * 4 + 3][p * 16 + g] };
    *(u16x4*)(dst + (size_t)d * LSEQ + l) = o;
  }
}

// ---------- RoPE cos/sin table ----------
__global__ void k_rope_table(const int* __restrict__ pos, float* __restrict__ tab, int pstride) {
  int i = blockIdx.x * 256 + threadIdx.x;   // l*64 + j
  int l = i >> 6, j = i & 63;
  float p = (float)pos[(size_t)l * pstride];
  float th = p * expf(-(float)j * 0.14391156642178528f);  // ln(10000)/64
  tab[2 * i + 0] = cosf(th);
  tab[2 * i + 1] = sinf(th);
}

// ---------- RoPE apply, x2 vectorized; Q pre-scaled by 1/sqrt(HD) ----------
__global__ void k_rope_apply(u16* __restrict__ qkv, const float* __restrict__ tab) {
  int i = blockIdx.x * 256 + threadIdx.x;   // rows(4096) x mat(2) x h(16) x dph(32)
  int dph = i & 31;
  int h = (i >> 5) & 15;
  int mat = (i >> 9) & 1;
  int row = i >> 10;
  int l = row & (LSEQ - 1);
  const float* t1 = tab + 2 * (l * 64 + dph);
  const float* t2 = tab + 2 * (l * 64 + 32 + dph);
  float s = mat ? 1.0f : 0.08838834764831845f;   // fold 1/sqrt(128) into Q
  size_t base = (size_t)row * NQK + mat * HIDDEN + h * HD + dph * 2;
  u16x2 xa = *(u16x2*)(qkv + base);
  u16x2 xb = *(u16x2*)(qkv + base + 64);
  float x1a = b2f(xa[0]), x1b = b2f(xa[1]), x2a = b2f(xb[0]), x2b = b2f(xb[1]);
  u16x2 oa = { f2b((t1[0] * x1a - t1[1] * x2a) * s), f2b((t1[0] * x1b - t1[1] * x2b) * s) };
  u16x2 ob = { f2b((t2[0] * x2a + t2[1] * x1a) * s), f2b((t2[0] * x2b + t2[1] * x1b) * s) };
  *(u16x2*)(qkv + base) = oa;
  *(u16x2*)(qkv + base + 64) = ob;
}

// ---------- bf16 GEMM, C = A[M][K] * Bt[N][K]^T, 128x128x32, 2-phase dbuf ----------
template<int BF16OUT>
__global__ __launch_bounds__(256) void k_gemm(const u16* __restrict__ A, const u16* __restrict__ Bt,
                                              void* __restrict__ Cv, int M, int N, int K) {
  __shared__ __align__(16) u16 As[2][128 * 32];
  __shared__ __align__(16) u16 Bs[2][128 * 32];
  const int tid = threadIdx.x;
  const int wid = tid >> 6, lane = tid & 63;
  const int l15 = lane & 15, l4 = lane >> 4;
  // bijective XCD swizzle (nwg % 8 == 0 for both launches)
  const int nbx = gridDim.x;
  const int nwg = nbx * gridDim.y;
  const int id = blockIdx.y * nbx + blockIdx.x;
  const int q = nwg >> 3;
  const int sid = (id & 7) * q + (id >> 3);
  const int bn = sid % nbx, bm = sid / nbx;
  const int wm = wid >> 1, wn = wid & 1;
  const u16* Ag = A + (size_t)bm * 128 * K;
  const u16* Bg = Bt + (size_t)bn * 128 * K;
  char* AsC = (char*)As; char* BsC = (char*)Bs;
  f32x4 acc[4][4] = {};

  auto stage = [&](int k0, int bf) {
    char* Ad = AsC + bf * 8192; char* Bd = BsC + bf * 8192;
    int c = wid * 64 + lane;
    gload16(Ag + (size_t)(c >> 2) * K + k0 + (c & 3) * 8, Ad + (wid * 64) * 16);
    gload16(Bg + (size_t)(c >> 2) * K + k0 + (c & 3) * 8, Bd + (wid * 64) * 16);
    int c2 = c + 256;
    gload16(Ag + (size_t)(c2 >> 2) * K + k0 + (c2 & 3) * 8, Ad + (256 + wid * 64) * 16);
    gload16(Bg + (size_t)(c2 >> 2) * K + k0 + (c2 & 3) * 8, Bd + (256 + wid * 64) * 16);
  };

  stage(0, 0);
  __syncthreads();
  int cur = 0;
  for (int k0 = 0; k0 < K; k0 += 32) {
    if (k0 + 32 < K) stage(k0 + 32, cur ^ 1);
    const u16* Ab = &As[cur][0];
    const u16* Bb = &Bs[cur][0];
    bf16x8 af[4], bfv[4];
#pragma unroll
    for (int mi = 0; mi < 4; ++mi)
      af[mi] = *(const bf16x8*)(Ab + (wm * 64 + mi * 16 + l15) * 32 + l4 * 8);
#pragma unroll
    for (int nj = 0; nj < 4; ++nj)
      bfv[nj] = *(const bf16x8*)(Bb + (wn * 64 + nj * 16 + l15) * 32 + l4 * 8);
#pragma unroll
    for (int mi = 0; mi < 4; ++mi)
#pragma unroll
      for (int nj = 0; nj < 4; ++nj)
        acc[mi][nj] = mfma16(af[mi], bfv[nj], acc[mi][nj]);
    __syncthreads();
    cur ^= 1;
  }

#pragma unroll
  for (int mi = 0; mi < 4; ++mi) {
#pragma unroll
    for (int nj = 0; nj < 4; ++nj) {
      int row0 = bm * 128 + wm * 64 + mi * 16 + l4 * 4;
      int col  = bn * 128 + wn * 64 + nj * 16 + l15;
#pragma unroll
      for (int r = 0; r < 4; ++r) {
        float v = acc[mi][nj][r];
        if (BF16OUT) ((u16*)Cv)[(size_t)(row0 + r) * N + col] = f2b(v);
        else         ((float*)Cv)[(size_t)(row0 + r) * N + col] = v;
      }
    }
  }
}

// ---------- flash attention: 8 waves x 16 q-rows, KV tile 64, V^T staged ----------
__global__ __launch_bounds__(512) void k_attn(const u16* __restrict__ qkv,
                                              const u16* __restrict__ vt,
                                              u16* __restrict__ aout) {
  __shared__ __align__(16) u16 Ks[64 * 128];    // [kv][d], XOR-swizzled per row
  __shared__ __align__(16) u16 Vs[128 * 64];    // V^T [d][kv], XOR-swizzled per row
  __shared__ __align__(16) u16 Ps[8 * 16 * 72]; // per-wave P, stride 72
  // XCD-grouped decode: all 16 q-tiles of one (b,h) share an XCD
  const int dcode = blockIdx.x;                 // 0..511
  const int xcd = dcode & 7, ix = dcode >> 3;
  const int bh = xcd * 4 + (ix >> 4);
  const int qt = ix & 15;
  const int b = bh >> 4, h = bh & 15;
  const int tid = threadIdx.x, w = tid >> 6, lane = tid & 63;
  const int l15 = lane & 15, l4 = lane >> 4;

  // Q fragments (pre-scaled), 16 rows per wave
  bf16x8 qf[4];
  {
    int qrow = qt * 128 + w * 16 + l15;
    const u16* qp = qkv + (size_t)(b * LSEQ + qrow) * NQK + h * HD;
#pragma unroll
    for (int ks = 0; ks < 4; ++ks)
      qf[ks] = *(const bf16x8*)(qp + ks * 32 + l4 * 8);
  }

  f32x4 acc_o[8] = {};
  float mrun[4], lrun[4];
#pragma unroll
  for (int r = 0; r < 4; ++r) { mrun[r] = -1e30f; lrun[r] = 0.f; }

  const u16* kb  = qkv + (size_t)b * LSEQ * NQK + HIDDEN + h * HD;
  const u16* vtb = vt + (size_t)bh * HD * LSEQ;
  char* KsC = (char*)Ks; char* VsC = (char*)Vs;
  const int qrow0 = qt * 128 + w * 16 + l4 * 4;
  const int ntiles = 2 * qt + 2;

  for (int t = 0; t < ntiles; ++t) {
    const int kv0 = t * 64;
    // stage K [64][128] and V^T [128][64]; 1024 16B-chunks each, 512 threads
#pragma unroll
    for (int p = 0; p < 2; ++p) {
      int cc = p * 512 + tid;
      int row = cc >> 4, sl = cc & 15;
      gload16(kb + (size_t)(kv0 + row) * NQK + ((sl ^ (row & 7)) * 8),
              KsC + (p * 512 + w * 64) * 16);
    }
#pragma unroll
    for (int p = 0; p < 2; ++p) {
      int cc = p * 512 + tid;
      int d = cc >> 3, sl = cc & 7;
      gload16(vtb + (size_t)d * LSEQ + kv0 + ((sl ^ (d & 7)) * 8),
              VsC + (p * 512 + w * 64) * 16);
    }
    __syncthreads();

    const bool active = (w * 16 + 15) >= (kv0 - qt * 128);
    if (active) {
      // S = Q K^T (Q pre-scaled)
      f32x4 accs[4] = {};
      __builtin_amdgcn_s_setprio(1);
#pragma unroll
      for (int ks = 0; ks < 4; ++ks) {
#pragma unroll
        for (int nj = 0; nj < 4; ++nj) {
          int row = nj * 16 + l15;
          int co = (ks * 64 + l4 * 16) ^ ((row & 7) << 4);
          bf16x8 kf = *(const bf16x8*)(KsC + row * 256 + co);
          accs[nj] = mfma16(qf[ks], kf, accs[nj]);
        }
      }
      __builtin_amdgcn_s_setprio(0);

      // online softmax
      float pv[4][4], newm[4];
      bool anych = false;
#pragma unroll
      for (int r = 0; r < 4; ++r) {
        float mx = -3e38f;
#pragma unroll
        for (int nj = 0; nj < 4; ++nj) {
          int kvcol = kv0 + nj * 16 + l15;
          float sv = (kvcol <= qrow0 + r) ? accs[nj][r] : -3e38f;
          pv[nj][r] = sv;
          mx = fmaxf(mx, sv);
        }
        mx = fmaxf(mx, __shfl_xor(mx, 1));
        mx = fmaxf(mx, __shfl_xor(mx, 2));
        mx = fmaxf(mx, __shfl_xor(mx, 4));
        mx = fmaxf(mx, __shfl_xor(mx, 8));
        newm[r] = fmaxf(mrun[r], mx);
        anych = anych || (newm[r] > mrun[r]);
      }
      if (__any(anych)) {   // wave-uniform; skip exact-no-op rescales
#pragma unroll
        for (int r = 0; r < 4; ++r) {
          float cf = __expf(mrun[r] - newm[r]);
          mrun[r] = newm[r];
          lrun[r] *= cf;
#pragma unroll
          for (int df = 0; df < 8; ++df)
            acc_o[df][r] *= cf;
        }
      }
#pragma unroll
      for (int r = 0; r < 4; ++r) {
        float s = 0.f;
#pragma unroll
        for (int nj = 0; nj < 4; ++nj) {
          float e = __expf(pv[nj][r] - mrun[r]);
          pv[nj][r] = e;
          s += e;
        }
        s += __shfl_xor(s, 1);
        s += __shfl_xor(s, 2);
        s += __shfl_xor(s, 4);
        s += __shfl_xor(s, 8);
        lrun[r] += s;
      }
      // P -> LDS (wave-local; no barrier needed before PV)
#pragma unroll
      for (int nj = 0; nj < 4; ++nj)
#pragma unroll
        for (int r = 0; r < 4; ++r)
          Ps[(w * 16 + l4 * 4 + r) * 72 + nj * 16 + l15] = f2b(pv[nj][r]);

      // O += P V  (V^T b-frags via swizzled ds_read_b128)
      bf16x8 pa[2];
#pragma unroll
      for (int ks2 = 0; ks2 < 2; ++ks2)
        pa[ks2] = *(const bf16x8*)(Ps + (w * 16 + l15) * 72 + ks2 * 32 + l4 * 8);
      __builtin_amdgcn_s_setprio(1);
#pragma unroll
      for (int df = 0; df < 8; ++df) {
#pragma unroll
        for (int ks2 = 0; ks2 < 2; ++ks2) {
          int vrow = df * 16 + l15;
          int co = (ks2 * 64 + l4 * 16) ^ ((vrow & 7) << 4);
          bf16x8 bv = *(const bf16x8*)(VsC + vrow * 128 + co);
          acc_o[df] = mfma16(pa[ks2], bv, acc_o[df]);
        }
      }
      __builtin_amdgcn_s_setprio(0);
    }
    __syncthreads();   // LDS consumed; safe to restage
  }

  // epilogue: O /= l, write bf16 [B*L][HIDDEN]
#pragma unroll
  for (int r = 0; r < 4; ++r) {
    float inv = 1.f / lrun[r];
    u16* op = aout + (size_t)(b * LSEQ + qrow0 + r) * HIDDEN + h * HD;
#pragma unroll
    for (int df = 0; df < 8; ++df)
      op[df * 16 + l15] = f2b(acc_o[df][r] * inv);
  }
}

extern "C" void kernel_launch(void* const* d_in, const int* in_sizes, int n_in,
                              void* d_out, int out_size, void* d_ws, size_t ws_size,
                              hipStream_t stream) {
  const float* hidden = (const float*)d_in[0];
  // d_in[1] = attention_mask: causal, applied analytically in k_attn
  const int*   pos = (const int*)d_in[2];
  const float* Wq = (const float*)d_in[3];
  const float* Wk = (const float*)d_in[4];
  const float* Wv = (const float*)d_in[5];
  const float* Wo = (const float*)d_in[6];
  float* out = (float*)d_out;

  char* ws = (char*)d_ws;
  u16* hbf   = (u16*)ws;                                  // [4096][2048] bf16 (reused as attn_out)
  u16* WT    = (u16*)(ws + 16777216);                     // [6144][2048] bf16 (dead after QKV GEMM)
  u16* vt    = WT;                                        // [32][128][2048] bf16 V^T (aliases WT)
  u16* WoT   = (u16*)(ws + 16777216 + 25165824);          // [2048][2048] bf16
  u16* qkv   = (u16*)(ws + 50331648);                     // [4096][6144] bf16
  float* tab = (float*)(ws + 100663296);                  // [2048][64] {cos,sin}
  u16* aout  = hbf;

  int pstride = (in_sizes[2] == LSEQ) ? 1 : 2;            // int32 vs int64-as-int-pairs

  k_f32_to_bf16<<<8192, 256, 0, stream>>>(hidden, hbf, 2097152);
  dim3 tg(32, 32);
  k_transpose_bf16<<<tg, 256, 0, stream>>>(Wq, WT,                   2048, 2048);
  k_transpose_bf16<<<tg, 256, 0, stream>>>(Wk, WT + 2048 * 2048,     2048, 2048);
  k_transpose_bf16<<<tg, 256, 0, stream>>>(Wv, WT + 2 * 2048 * 2048, 2048, 2048);
  k_transpose_bf16<<<tg, 256, 0, stream>>>(Wo, WoT,                  2048, 2048);
  k_rope_table<<<512, 256, 0, stream>>>(pos, tab, pstride);
  k_gemm<1><<<dim3(48, 32), 256, 0, stream>>>(hbf, WT, qkv, 4096, 6144, 2048);
  k_transpose_v<<<dim3(32, 2, 32), 256, 0, stream>>>(qkv, vt);
  k_rope_apply<<<16384, 256, 0, stream>>>(qkv, tab);
  k_attn<<<512, 512, 0, stream>>>(qkv, vt, aout);
  k_gemm<0><<<dim3(16, 32), 256, 0, stream>>>(aout, WoT, out, 4096, 2048, 2048);
}

// Round 3
// 316.556 us; speedup vs baseline: 1.3794x; 1.1728x over previous
//
#include <hip/hip_runtime.h>
#include <stdint.h>

typedef uint16_t u16;
typedef __attribute__((ext_vector_type(4))) float f32x4;
typedef __attribute__((ext_vector_type(2))) unsigned short u16x2;
typedef __attribute__((ext_vector_type(4))) unsigned short u16x4;
typedef __attribute__((ext_vector_type(8))) __bf16 bf16x8;

#define HIDDEN 2048
#define LSEQ   2048
#define NH     16
#define HD     128
#define NQK    6144   // 3*HIDDEN, qkv row stride

// ---------- bf16 helpers (RNE) ----------
__device__ __forceinline__ u16 f2b(float f) {
  union { float f; uint32_t u; } v; v.f = f;
  uint32_t r = v.u + 0x7fffu + ((v.u >> 16) & 1u);
  return (u16)(r >> 16);
}
__device__ __forceinline__ float b2f(u16 h) {
  union { uint32_t u; float f; } v; v.u = ((uint32_t)h) << 16;
  return v.f;
}

__device__ __forceinline__ void gload16(const void* g, void* l) {
  __builtin_amdgcn_global_load_lds((const __attribute__((address_space(1))) void*)g,
                                   (__attribute__((address_space(3))) void*)l, 16, 0, 0);
}
__device__ __forceinline__ f32x4 mfma16(bf16x8 a, bf16x8 b, f32x4 c) {
  return __builtin_amdgcn_mfma_f32_16x16x32_bf16(a, b, c, 0, 0, 0);
}

// ---------- f32 -> bf16 bulk convert ----------
__global__ void k_f32_to_bf16(const float* __restrict__ in, u16* __restrict__ out, int n4) {
  int i = blockIdx.x * 256 + threadIdx.x;
  if (i >= n4) return;
  float4 v = ((const float4*)in)[i];
  u16x4 o = { f2b(v.x), f2b(v.y), f2b(v.z), f2b(v.w) };
  ((u16x4*)out)[i] = o;
}

// ---------- transpose + convert: W[R][C] f32 -> WT[C][R] bf16 ----------
__global__ __launch_bounds__(256) void k_transpose_bf16(const float* __restrict__ W,
                                                        u16* __restrict__ WT, int R, int C) {
  __shared__ u16 tile[64][65];
  const int bx = blockIdx.x, by = blockIdx.y;
  const int t = threadIdx.x;
  const int g = t >> 4, k = t & 15;
#pragma unroll
  for (int p = 0; p < 4; ++p) {
    int r = by * 64 + p * 16 + g;
    int c = bx * 64 + k * 4;
    float4 v = *(const float4*)(W + (size_t)r * C + c);
    tile[p * 16 + g][k * 4 + 0] = f2b(v.x);
    tile[p * 16 + g][k * 4 + 1] = f2b(v.y);
    tile[p * 16 + g][k * 4 + 2] = f2b(v.z);
    tile[p * 16 + g][k * 4 + 3] = f2b(v.w);
  }
  __syncthreads();
#pragma unroll
  for (int p = 0; p < 4; ++p) {
    int n = bx * 64 + p * 16 + g;
    int kk = by * 64 + k * 4;
    u16x4 o = { tile[k * 4 + 0][p * 16 + g], tile[k * 4 + 1][p * 16 + g],
                tile[k * 4 + 2][p * 16 + g], tile[k * 4 + 3][p * 16 + g] };
    *(u16x4*)(WT + (size_t)n * R + kk) = o;
  }
}

// ---------- V transpose: qkv V part [b][l][h][d] -> vt[b][h][d][l] (bf16) ----------
__global__ __launch_bounds__(256) void k_transpose_v(const u16* __restrict__ qkv,
                                                     u16* __restrict__ vt) {
  __shared__ u16 tile[64][65];
  const int lt = blockIdx.x;        // l tile (64)
  const int dt = blockIdx.y;        // d tile (64)
  const int bh = blockIdx.z;        // b*16+h
  const int t = threadIdx.x;
  const int g = t >> 4, k = t & 15;
  const u16* src = qkv + (size_t)(bh >> 4) * LSEQ * NQK + 2 * HIDDEN + (bh & 15) * HD;
#pragma unroll
  for (int p = 0; p < 4; ++p) {
    int l = lt * 64 + p * 16 + g;
    int d = dt * 64 + k * 4;
    u16x4 v = *(const u16x4*)(src + (size_t)l * NQK + d);
    tile[p * 16 + g][k * 4 + 0] = v[0];
    tile[p * 16 + g][k * 4 + 1] = v[1];
    tile[p * 16 + g][k * 4 + 2] = v[2];
    tile[p * 16 + g][k * 4 + 3] = v[3];
  }
  __syncthreads();
  u16* dst = vt + (size_t)bh * HD * LSEQ;
#pragma unroll
  for (int p = 0; p < 4; ++p) {
    int d = dt * 64 + p * 16 + g;
    int l = lt * 64 + k * 4;
    u16x4 o = { tile[k * 4 + 0][p * 16 + g], tile[k * 4 + 1][p * 16 + g],
                tile[k * 4 + 2][p * 16 + g], tile[k * 4 + 3][p * 16 + g] };
    *(u16x4*)(dst + (size_t)d * LSEQ + l) = o;
  }
}

// ---------- RoPE cos/sin table ----------
__global__ void k_rope_table(const int* __restrict__ pos, float* __restrict__ tab, int pstride) {
  int i = blockIdx.x * 256 + threadIdx.x;   // l*64 + j
  int l = i >> 6, j = i & 63;
  float p = (float)pos[(size_t)l * pstride];
  float th = p * expf(-(float)j * 0.14391156642178528f);  // ln(10000)/64
  tab[2 * i + 0] = cosf(th);
  tab[2 * i + 1] = sinf(th);
}

// ---------- RoPE apply, x2 vectorized; Q pre-scaled by 1/sqrt(HD) ----------
__global__ void k_rope_apply(u16* __restrict__ qkv, const float* __restrict__ tab) {
  int i = blockIdx.x * 256 + threadIdx.x;   // rows(4096) x mat(2) x h(16) x dph(32)
  int dph = i & 31;
  int h = (i >> 5) & 15;
  int mat = (i >> 9) & 1;
  int row = i >> 10;
  int l = row & (LSEQ - 1);
  const float* t1 = tab + 2 * (l * 64 + dph);
  const float* t2 = tab + 2 * (l * 64 + 32 + dph);
  float s = mat ? 1.0f : 0.08838834764831845f;   // fold 1/sqrt(128) into Q
  size_t base = (size_t)row * NQK + mat * HIDDEN + h * HD + dph * 2;
  u16x2 xa = *(u16x2*)(qkv + base);
  u16x2 xb = *(u16x2*)(qkv + base + 64);
  float x1a = b2f(xa[0]), x1b = b2f(xa[1]), x2a = b2f(xb[0]), x2b = b2f(xb[1]);
  u16x2 oa = { f2b((t1[0] * x1a - t1[1] * x2a) * s), f2b((t1[0] * x1b - t1[1] * x2b) * s) };
  u16x2 ob = { f2b((t2[0] * x2a + t2[1] * x1a) * s), f2b((t2[0] * x2b + t2[1] * x1b) * s) };
  *(u16x2*)(qkv + base) = oa;
  *(u16x2*)(qkv + base + 64) = ob;
}

// ---------- bf16 GEMM, C = A[M][K] * Bt[N][K]^T, 128x128x32, 2-phase dbuf ----------
template<int BF16OUT>
__global__ __launch_bounds__(256) void k_gemm(const u16* __restrict__ A, const u16* __restrict__ Bt,
                                              void* __restrict__ Cv, int M, int N, int K) {
  __shared__ __align__(16) u16 As[2][128 * 32];
  __shared__ __align__(16) u16 Bs[2][128 * 32];
  const int tid = threadIdx.x;
  const int wid = tid >> 6, lane = tid & 63;
  const int l15 = lane & 15, l4 = lane >> 4;
  // bijective XCD swizzle (nwg % 8 == 0 for both launches)
  const int nbx = gridDim.x;
  const int nwg = nbx * gridDim.y;
  const int id = blockIdx.y * nbx + blockIdx.x;
  const int q = nwg >> 3;
  const int sid = (id & 7) * q + (id >> 3);
  const int bn = sid % nbx, bm = sid / nbx;
  const int wm = wid >> 1, wn = wid & 1;
  const u16* Ag = A + (size_t)bm * 128 * K;
  const u16* Bg = Bt + (size_t)bn * 128 * K;
  char* AsC = (char*)As; char* BsC = (char*)Bs;
  f32x4 acc[4][4] = {};

  auto stage = [&](int k0, int bf) {
    char* Ad = AsC + bf * 8192; char* Bd = BsC + bf * 8192;
    int c = wid * 64 + lane;
    gload16(Ag + (size_t)(c >> 2) * K + k0 + (c & 3) * 8, Ad + (wid * 64) * 16);
    gload16(Bg + (size_t)(c >> 2) * K + k0 + (c & 3) * 8, Bd + (wid * 64) * 16);
    int c2 = c + 256;
    gload16(Ag + (size_t)(c2 >> 2) * K + k0 + (c2 & 3) * 8, Ad + (256 + wid * 64) * 16);
    gload16(Bg + (size_t)(c2 >> 2) * K + k0 + (c2 & 3) * 8, Bd + (256 + wid * 64) * 16);
  };

  stage(0, 0);
  __syncthreads();
  int cur = 0;
  for (int k0 = 0; k0 < K; k0 += 32) {
    if (k0 + 32 < K) stage(k0 + 32, cur ^ 1);
    const u16* Ab = &As[cur][0];
    const u16* Bb = &Bs[cur][0];
    bf16x8 af[4], bfv[4];
#pragma unroll
    for (int mi = 0; mi < 4; ++mi)
      af[mi] = *(const bf16x8*)(Ab + (wm * 64 + mi * 16 + l15) * 32 + l4 * 8);
#pragma unroll
    for (int nj = 0; nj < 4; ++nj)
      bfv[nj] = *(const bf16x8*)(Bb + (wn * 64 + nj * 16 + l15) * 32 + l4 * 8);
#pragma unroll
    for (int mi = 0; mi < 4; ++mi)
#pragma unroll
      for (int nj = 0; nj < 4; ++nj)
        acc[mi][nj] = mfma16(af[mi], bfv[nj], acc[mi][nj]);
    __syncthreads();
    cur ^= 1;
  }

#pragma unroll
  for (int mi = 0; mi < 4; ++mi) {
#pragma unroll
    for (int nj = 0; nj < 4; ++nj) {
      int row0 = bm * 128 + wm * 64 + mi * 16 + l4 * 4;
      int col  = bn * 128 + wn * 64 + nj * 16 + l15;
#pragma unroll
      for (int r = 0; r < 4; ++r) {
        float v = acc[mi][nj][r];
        if (BF16OUT) ((u16*)Cv)[(size_t)(row0 + r) * N + col] = f2b(v);
        else         ((float*)Cv)[(size_t)(row0 + r) * N + col] = v;
      }
    }
  }
}

// ---------- flash attention: 256 blocks, 8 waves, paired q-tiles, dbuf single-barrier ----------
__global__ __launch_bounds__(512) void k_attn(const u16* __restrict__ qkv,
                                              const u16* __restrict__ vt,
                                              u16* __restrict__ aout) {
  __shared__ __align__(16) u16 Ks[2][64 * 128];  // [kv][d], XOR-swizzled rows
  __shared__ __align__(16) u16 Vs[2][128 * 64];  // V^T [d][kv], XOR-swizzled rows
  __shared__ __align__(16) u16 Ps[8 * 16 * 72];  // per-wave P, stride 72
  const int bid = blockIdx.x;                    // 256 blocks
  const int bh = bid >> 3, pairi = bid & 7;
  const int b = bh >> 4, h = bh & 15;
  const int qtA = pairi, qtB = 15 - pairi;       // paired q-tiles: uniform total work
  const int tid = threadIdx.x, w = tid >> 6, lane = tid & 63;
  const int l15 = lane & 15, l4 = lane >> 4;

  // Q fragments (pre-scaled by 1/sqrt(d) in RoPE), 16 rows per wave per tile
  bf16x8 qfA[4], qfB[4];
  {
    const u16* qpA = qkv + (size_t)(b * LSEQ + qtA * 128 + w * 16 + l15) * NQK + h * HD;
    const u16* qpB = qkv + (size_t)(b * LSEQ + qtB * 128 + w * 16 + l15) * NQK + h * HD;
#pragma unroll
    for (int ks = 0; ks < 4; ++ks) {
      qfA[ks] = *(const bf16x8*)(qpA + ks * 32 + l4 * 8);
      qfB[ks] = *(const bf16x8*)(qpB + ks * 32 + l4 * 8);
    }
  }

  f32x4 accA[8] = {}, accB[8] = {};
  float mA[4], lA[4], mB[4], lB[4];
#pragma unroll
  for (int r = 0; r < 4; ++r) { mA[r] = -1e30f; lA[r] = 0.f; mB[r] = -1e30f; lB[r] = 0.f; }

  const u16* kb  = qkv + (size_t)b * LSEQ * NQK + HIDDEN + h * HD;
  const u16* vtb = vt + (size_t)bh * HD * LSEQ;
  const int ntA = 2 * qtA + 2, ntB = 2 * qtB + 2;

  auto stage = [&](int t, int bf) {
    const int kv0 = t * 64;
    char* Kd = (char*)(&Ks[bf][0]);
    char* Vd = (char*)(&Vs[bf][0]);
#pragma unroll
    for (int p = 0; p < 2; ++p) {
      int cc = p * 512 + tid;
      int row = cc >> 4, sl = cc & 15;
      gload16(kb + (size_t)(kv0 + row) * NQK + ((sl ^ (row & 7)) * 8), Kd + (p * 512 + w * 64) * 16);
    }
#pragma unroll
    for (int p = 0; p < 2; ++p) {
      int cc = p * 512 + tid;
      int d = cc >> 3, sl = cc & 7;
      gload16(vtb + (size_t)d * LSEQ + kv0 + ((sl ^ (d & 7)) * 8), Vd + (p * 512 + w * 64) * 16);
    }
  };

  auto computeTile = [&](const bf16x8 (&qf)[4], f32x4 (&acc_o)[8], float (&mrun)[4],
                         float (&lrun)[4], int qt, int kv0, int cur) {
    const int qbase = qt * 128 + w * 16;
    if (kv0 > qbase + 15) return;                // wave has no valid cols this tile
    const char* KsC = (const char*)(&Ks[cur][0]);
    const char* VsC = (const char*)(&Vs[cur][0]);

    f32x4 accs[4] = {};
    __builtin_amdgcn_s_setprio(1);
#pragma unroll
    for (int ks = 0; ks < 4; ++ks) {
#pragma unroll
      for (int nj = 0; nj < 4; ++nj) {
        int row = nj * 16 + l15;
        int co = (ks * 64 + l4 * 16) ^ ((row & 7) << 4);
        bf16x8 kf = *(const bf16x8*)(KsC + row * 256 + co);
        accs[nj] = mfma16(qf[ks], kf, accs[nj]);
      }
    }
    __builtin_amdgcn_s_setprio(0);

    const int qrow0 = qbase + l4 * 4;
    float pv[4][4], pmax[4];
    if (kv0 + 63 <= qbase) {                     // interior tile: no masking
#pragma unroll
      for (int r = 0; r < 4; ++r) {
        pmax[r] = fmaxf(fmaxf(accs[0][r], accs[1][r]), fmaxf(accs[2][r], accs[3][r]));
#pragma unroll
        for (int nj = 0; nj < 4; ++nj) pv[nj][r] = accs[nj][r];
      }
    } else {
#pragma unroll
      for (int r = 0; r < 4; ++r) {
        float mx = -3e38f;
#pragma unroll
        for (int nj = 0; nj < 4; ++nj) {
          int kvcol = kv0 + nj * 16 + l15;
          float sv = (kvcol <= qrow0 + r) ? accs[nj][r] : -3e38f;
          pv[nj][r] = sv;
          mx = fmaxf(mx, sv);
        }
        pmax[r] = mx;
      }
    }
#pragma unroll
    for (int r = 0; r < 4; ++r) {
      pmax[r] = fmaxf(pmax[r], __shfl_xor(pmax[r], 1));
      pmax[r] = fmaxf(pmax[r], __shfl_xor(pmax[r], 2));
      pmax[r] = fmaxf(pmax[r], __shfl_xor(pmax[r], 4));
      pmax[r] = fmaxf(pmax[r], __shfl_xor(pmax[r], 8));
    }
    // T13 defer-max: rescale only when tile max exceeds running max by >8
    bool need = false;
#pragma unroll
    for (int r = 0; r < 4; ++r) need = need || (pmax[r] > mrun[r] + 8.f);
    if (__any(need)) {
#pragma unroll
      for (int r = 0; r < 4; ++r) {
        float nm = fmaxf(mrun[r], pmax[r]);
        float cf = __expf(mrun[r] - nm);
        mrun[r] = nm;
        lrun[r] *= cf;
#pragma unroll
        for (int df = 0; df < 8; ++df) acc_o[df][r] *= cf;
      }
    }
#pragma unroll
    for (int r = 0; r < 4; ++r) {
      float s = 0.f;
#pragma unroll
      for (int nj = 0; nj < 4; ++nj) {
        float e = __expf(pv[nj][r] - mrun[r]);
        pv[nj][r] = e;
        s += e;
      }
      s += __shfl_xor(s, 1);
      s += __shfl_xor(s, 2);
      s += __shfl_xor(s, 4);
      s += __shfl_xor(s, 8);
      lrun[r] += s;
    }
    // P -> LDS (wave-private rows; no cross-wave barrier needed)
#pragma unroll
    for (int nj = 0; nj < 4; ++nj)
#pragma unroll
      for (int r = 0; r < 4; ++r)
        Ps[(w * 16 + l4 * 4 + r) * 72 + nj * 16 + l15] = f2b(pv[nj][r]);

    bf16x8 pa[2];
#pragma unroll
    for (int ks2 = 0; ks2 < 2; ++ks2)
      pa[ks2] = *(const bf16x8*)(Ps + (w * 16 + l15) * 72 + ks2 * 32 + l4 * 8);
    __builtin_amdgcn_s_setprio(1);
#pragma unroll
    for (int df = 0; df < 8; ++df) {
#pragma unroll
      for (int ks2 = 0; ks2 < 2; ++ks2) {
        int vrow = df * 16 + l15;
        int co = (ks2 * 64 + l4 * 16) ^ ((vrow & 7) << 4);
        bf16x8 bv = *(const bf16x8*)(VsC + vrow * 128 + co);
        acc_o[df] = mfma16(pa[ks2], bv, acc_o[df]);
      }
    }
    __builtin_amdgcn_s_setprio(0);
  };

  stage(0, 0);
  __syncthreads();
  int cur = 0;
  for (int t = 0; t < ntB; ++t) {
    if (t + 1 < ntB) stage(t + 1, cur ^ 1);      // prefetch next tile (other buffer)
    const int kv0 = t * 64;
    if (t < ntA) computeTile(qfA, accA, mA, lA, qtA, kv0, cur);
    computeTile(qfB, accB, mB, lB, qtB, kv0, cur);
    __syncthreads();                             // drains prefetch + guards buffer reuse
    cur ^= 1;
  }

  // epilogue: O /= l, write bf16 [B*L][HIDDEN]
#pragma unroll
  for (int r = 0; r < 4; ++r) {
    float invA = 1.f / lA[r];
    float invB = 1.f / lB[r];
    u16* opA = aout + (size_t)(b * LSEQ + qtA * 128 + w * 16 + l4 * 4 + r) * HIDDEN + h * HD;
    u16* opB = aout + (size_t)(b * LSEQ + qtB * 128 + w * 16 + l4 * 4 + r) * HIDDEN + h * HD;
#pragma unroll
    for (int df = 0; df < 8; ++df) {
      opA[df * 16 + l15] = f2b(accA[df][r] * invA);
      opB[df * 16 + l15] = f2b(accB[df][r] * invB);
    }
  }
}

extern "C" void kernel_launch(void* const* d_in, const int* in_sizes, int n_in,
                              void* d_out, int out_size, void* d_ws, size_t ws_size,
                              hipStream_t stream) {
  const float* hidden = (const float*)d_in[0];
  // d_in[1] = attention_mask: causal, applied analytically in k_attn
  const int*   pos = (const int*)d_in[2];
  const float* Wq = (const float*)d_in[3];
  const float* Wk = (const float*)d_in[4];
  const float* Wv = (const float*)d_in[5];
  const float* Wo = (const float*)d_in[6];
  float* out = (float*)d_out;

  char* ws = (char*)d_ws;
  u16* hbf   = (u16*)ws;                                  // [4096][2048] bf16 (reused as attn_out)
  u16* WT    = (u16*)(ws + 16777216);                     // [6144][2048] bf16 (dead after QKV GEMM)
  u16* vt    = WT;                                        // [32][128][2048] bf16 V^T (aliases WT)
  u16* WoT   = (u16*)(ws + 16777216 + 25165824);          // [2048][2048] bf16
  u16* qkv   = (u16*)(ws + 50331648);                     // [4096][6144] bf16
  float* tab = (float*)(ws + 100663296);                  // [2048][64] {cos,sin}
  u16* aout  = hbf;

  int pstride = (in_sizes[2] == LSEQ) ? 1 : 2;            // int32 vs int64-as-int-pairs

  k_f32_to_bf16<<<8192, 256, 0, stream>>>(hidden, hbf, 2097152);
  dim3 tg(32, 32);
  k_transpose_bf16<<<tg, 256, 0, stream>>>(Wq, WT,                   2048, 2048);
  k_transpose_bf16<<<tg, 256, 0, stream>>>(Wk, WT + 2048 * 2048,     2048, 2048);
  k_transpose_bf16<<<tg, 256, 0, stream>>>(Wv, WT + 2 * 2048 * 2048, 2048, 2048);
  k_transpose_bf16<<<tg, 256, 0, stream>>>(Wo, WoT,                  2048, 2048);
  k_rope_table<<<512, 256, 0, stream>>>(pos, tab, pstride);
  k_gemm<1><<<dim3(48, 32), 256, 0, stream>>>(hbf, WT, qkv, 4096, 6144, 2048);
  k_transpose_v<<<dim3(32, 2, 32), 256, 0, stream>>>(qkv, vt);
  k_rope_apply<<<16384, 256, 0, stream>>>(qkv, tab);
  k_attn<<<256, 512, 0, stream>>>(qkv, vt, aout);
  k_gemm<0><<<dim3(16, 32), 256, 0, stream>>>(aout, WoT, out, 4096, 2048, 2048);
}

// Round 4
// 295.307 us; speedup vs baseline: 1.4786x; 1.0720x over previous
//
#include <hip/hip_runtime.h>
#include <stdint.h>

typedef uint16_t u16;
typedef __attribute__((ext_vector_type(4))) float f32x4;
typedef __attribute__((ext_vector_type(2))) unsigned short u16x2;
typedef __attribute__((ext_vector_type(4))) unsigned short u16x4;
typedef __attribute__((ext_vector_type(8))) __bf16 bf16x8;

#define HIDDEN 2048
#define LSEQ   2048
#define NH     16
#define HD     128
#define NQK    6144   // 3*HIDDEN, qkv row stride

// ---------- bf16 helpers (RNE) ----------
__device__ __forceinline__ u16 f2b(float f) {
  union { float f; uint32_t u; } v; v.f = f;
  uint32_t r = v.u + 0x7fffu + ((v.u >> 16) & 1u);
  return (u16)(r >> 16);
}
__device__ __forceinline__ float b2f(u16 h) {
  union { uint32_t u; float f; } v; v.u = ((uint32_t)h) << 16;
  return v.f;
}

__device__ __forceinline__ void gload16(const void* g, void* l) {
  __builtin_amdgcn_global_load_lds((const __attribute__((address_space(1))) void*)g,
                                   (__attribute__((address_space(3))) void*)l, 16, 0, 0);
}
__device__ __forceinline__ f32x4 mfma16(bf16x8 a, bf16x8 b, f32x4 c) {
  return __builtin_amdgcn_mfma_f32_16x16x32_bf16(a, b, c, 0, 0, 0);
}

// ---------- f32 -> bf16 bulk convert ----------
__global__ void k_f32_to_bf16(const float* __restrict__ in, u16* __restrict__ out, int n4) {
  int i = blockIdx.x * 256 + threadIdx.x;
  if (i >= n4) return;
  float4 v = ((const float4*)in)[i];
  u16x4 o = { f2b(v.x), f2b(v.y), f2b(v.z), f2b(v.w) };
  ((u16x4*)out)[i] = o;
}

// ---------- transpose + convert: W[R][C] f32 -> WT[C][R] bf16 ----------
__global__ __launch_bounds__(256) void k_transpose_bf16(const float* __restrict__ W,
                                                        u16* __restrict__ WT, int R, int C) {
  __shared__ u16 tile[64][65];
  const int bx = blockIdx.x, by = blockIdx.y;
  const int t = threadIdx.x;
  const int g = t >> 4, k = t & 15;
#pragma unroll
  for (int p = 0; p < 4; ++p) {
    int r = by * 64 + p * 16 + g;
    int c = bx * 64 + k * 4;
    float4 v = *(const float4*)(W + (size_t)r * C + c);
    tile[p * 16 + g][k * 4 + 0] = f2b(v.x);
    tile[p * 16 + g][k * 4 + 1] = f2b(v.y);
    tile[p * 16 + g][k * 4 + 2] = f2b(v.z);
    tile[p * 16 + g][k * 4 + 3] = f2b(v.w);
  }
  __syncthreads();
#pragma unroll
  for (int p = 0; p < 4; ++p) {
    int n = bx * 64 + p * 16 + g;
    int kk = by * 64 + k * 4;
    u16x4 o = { tile[k * 4 + 0][p * 16 + g], tile[k * 4 + 1][p * 16 + g],
                tile[k * 4 + 2][p * 16 + g], tile[k * 4 + 3][p * 16 + g] };
    *(u16x4*)(WT + (size_t)n * R + kk) = o;
  }
}

// ---------- V transpose: qkv V part [b][l][h][d] -> vt[b][h][d][l] (bf16) ----------
__global__ __launch_bounds__(256) void k_transpose_v(const u16* __restrict__ qkv,
                                                     u16* __restrict__ vt) {
  __shared__ u16 tile[64][65];
  const int lt = blockIdx.x;        // l tile (64)
  const int dt = blockIdx.y;        // d tile (64)
  const int bh = blockIdx.z;        // b*16+h
  const int t = threadIdx.x;
  const int g = t >> 4, k = t & 15;
  const u16* src = qkv + (size_t)(bh >> 4) * LSEQ * NQK + 2 * HIDDEN + (bh & 15) * HD;
#pragma unroll
  for (int p = 0; p < 4; ++p) {
    int l = lt * 64 + p * 16 + g;
    int d = dt * 64 + k * 4;
    u16x4 v = *(const u16x4*)(src + (size_t)l * NQK + d);
    tile[p * 16 + g][k * 4 + 0] = v[0];
    tile[p * 16 + g][k * 4 + 1] = v[1];
    tile[p * 16 + g][k * 4 + 2] = v[2];
    tile[p * 16 + g][k * 4 + 3] = v[3];
  }
  __syncthreads();
  u16* dst = vt + (size_t)bh * HD * LSEQ;
#pragma unroll
  for (int p = 0; p < 4; ++p) {
    int d = dt * 64 + p * 16 + g;
    int l = lt * 64 + k * 4;
    u16x4 o = { tile[k * 4 + 0][p * 16 + g], tile[k * 4 + 1][p * 16 + g],
                tile[k * 4 + 2][p * 16 + g], tile[k * 4 + 3][p * 16 + g] };
    *(u16x4*)(dst + (size_t)d * LSEQ + l) = o;
  }
}

// ---------- RoPE cos/sin table ----------
__global__ void k_rope_table(const int* __restrict__ pos, float* __restrict__ tab, int pstride) {
  int i = blockIdx.x * 256 + threadIdx.x;   // l*64 + j
  int l = i >> 6, j = i & 63;
  float p = (float)pos[(size_t)l * pstride];
  float th = p * expf(-(float)j * 0.14391156642178528f);  // ln(10000)/64
  tab[2 * i + 0] = cosf(th);
  tab[2 * i + 1] = sinf(th);
}

// ---------- RoPE apply, x2 vectorized; Q pre-scaled by 1/sqrt(HD) ----------
__global__ void k_rope_apply(u16* __restrict__ qkv, const float* __restrict__ tab) {
  int i = blockIdx.x * 256 + threadIdx.x;   // rows(4096) x mat(2) x h(16) x dph(32)
  int dph = i & 31;
  int h = (i >> 5) & 15;
  int mat = (i >> 9) & 1;
  int row = i >> 10;
  int l = row & (LSEQ - 1);
  const float* t1 = tab + 2 * (l * 64 + dph);
  const float* t2 = tab + 2 * (l * 64 + 32 + dph);
  float s = mat ? 1.0f : 0.08838834764831845f;   // fold 1/sqrt(128) into Q
  size_t base = (size_t)row * NQK + mat * HIDDEN + h * HD + dph * 2;
  u16x2 xa = *(u16x2*)(qkv + base);
  u16x2 xb = *(u16x2*)(qkv + base + 64);
  float x1a = b2f(xa[0]), x1b = b2f(xa[1]), x2a = b2f(xb[0]), x2b = b2f(xb[1]);
  u16x2 oa = { f2b((t1[0] * x1a - t1[1] * x2a) * s), f2b((t1[0] * x1b - t1[1] * x2b) * s) };
  u16x2 ob = { f2b((t2[0] * x2a + t2[1] * x1a) * s), f2b((t2[0] * x2b + t2[1] * x1b) * s) };
  *(u16x2*)(qkv + base) = oa;
  *(u16x2*)(qkv + base + 64) = ob;
}

// ---------- bf16 GEMM, C = A[M][K] * Bt[N][K]^T ----------
// BM=128 BN=256 BK=64, 8 waves (2Mx4N), per-wave 64x64 out.
// 3 LDS buffers, stage K-tile t+2 during compute of t (never a live buffer).
// Counted s_waitcnt vmcnt(6) + raw s_barrier once per K-tile (no vmcnt-0 drain).
// LDS swizzle: chunk (row, s) stored at s^(row&7) via pre-swizzled global source.
template<int BF16OUT>
__global__ __launch_bounds__(512, 2) void k_gemm2(const u16* __restrict__ A,
                                                  const u16* __restrict__ Bt,
                                                  void* __restrict__ Cv,
                                                  int M, int N, int K) {
  __shared__ __align__(16) char lds[147456];   // A: 3x16KB @0, B: 3x32KB @48K
  const int tid = threadIdx.x, w = tid >> 6, lane = tid & 63;
  const int l15 = lane & 15, l4 = lane >> 4;
  const int wm = w >> 2, wn = w & 3;
  // bijective XCD swizzle (nwg % 8 == 0 for both launches)
  const int nbx = gridDim.x;
  const int nwg = nbx * gridDim.y;
  const int id = blockIdx.y * nbx + blockIdx.x;
  const int qq = nwg >> 3;
  const int sid = (id & 7) * qq + (id >> 3);
  const int bn = sid % nbx, bm = sid / nbx;
  const u16* Ag = A + (size_t)bm * 128 * K;
  const u16* Bg = Bt + (size_t)bn * 256 * K;
  const int r7 = (tid >> 3) & 7;                 // staging row&7 (uniform per thread)
  const int sw0 = ((0 + l4) ^ (l15 & 7)) * 16;   // ks=0 swizzled subchunk byte off
  const int sw1 = ((4 + l4) ^ (l15 & 7)) * 16;   // ks=1

  auto stageA = [&](int kt, int buf) {
    char* dst = lds + buf * 16384;
    const int k0 = kt << 6;
#pragma unroll
    for (int i = 0; i < 2; ++i) {
      int c = i * 512 + tid;
      int row = c >> 3, s = (c & 7) ^ r7;
      gload16(Ag + (size_t)row * K + k0 + s * 8, dst + (i * 512 + w * 64) * 16);
    }
  };
  auto stageBh = [&](int kt, int buf, int half) {
    char* dst = lds + 49152 + buf * 32768;
    const int k0 = kt << 6;
#pragma unroll
    for (int i = 0; i < 2; ++i) {
      int c = half * 1024 + i * 512 + tid;
      int row = c >> 3, s = (c & 7) ^ r7;
      gload16(Bg + (size_t)row * K + k0 + s * 8, dst + (half * 1024 + i * 512 + w * 64) * 16);
    }
  };

  const int NT = K >> 6;
  stageA(0, 0); stageBh(0, 0, 0); stageBh(0, 0, 1);
  stageA(1, 1); stageBh(1, 1, 0); stageBh(1, 1, 1);
  asm volatile("s_waitcnt vmcnt(6)" ::: "memory");   // K-tile 0 landed; KT1 in flight
  __builtin_amdgcn_s_barrier();
  asm volatile("" ::: "memory");

  f32x4 acc[4][4] = {};
  int buf = 0, sbuf = 2;
  for (int t = 0; t < NT; ++t) {
    const char* Ab = lds + buf * 16384;
    const char* Bb = lds + 49152 + buf * 32768;
    const bool doStage = (t + 2 < NT);
    bf16x8 af[4][2], bfr[4][2];
    auto rdA = [&](int mi, int ks) {
      return *(const bf16x8*)(Ab + ((wm * 64 + mi * 16 + l15) << 7) + (ks ? sw1 : sw0));
    };
    auto rdB = [&](int nj, int ks) {
      return *(const bf16x8*)(Bb + ((wn * 64 + nj * 16 + l15) << 7) + (ks ? sw1 : sw0));
    };

    // ---- phase 0: read A mi{0,1}, B nj{0,1}; stage A(t+2); MFMA mi01 x nj01
#pragma unroll
    for (int mi = 0; mi < 2; ++mi) { af[mi][0] = rdA(mi, 0); af[mi][1] = rdA(mi, 1); }
#pragma unroll
    for (int nj = 0; nj < 2; ++nj) { bfr[nj][0] = rdB(nj, 0); bfr[nj][1] = rdB(nj, 1); }
    if (doStage) stageA(t + 2, sbuf);
    __builtin_amdgcn_s_setprio(1);
#pragma unroll
    for (int mi = 0; mi < 2; ++mi)
#pragma unroll
      for (int nj = 0; nj < 2; ++nj) {
        acc[mi][nj] = mfma16(af[mi][0], bfr[nj][0], acc[mi][nj]);
        acc[mi][nj] = mfma16(af[mi][1], bfr[nj][1], acc[mi][nj]);
      }
    __builtin_amdgcn_s_setprio(0);

    // ---- phase 1: read B nj{2,3}; stage B(t+2) half0; MFMA mi01 x nj23
#pragma unroll
    for (int nj = 2; nj < 4; ++nj) { bfr[nj][0] = rdB(nj, 0); bfr[nj][1] = rdB(nj, 1); }
    if (doStage) stageBh(t + 2, sbuf, 0);
    __builtin_amdgcn_s_setprio(1);
#pragma unroll
    for (int mi = 0; mi < 2; ++mi)
#pragma unroll
      for (int nj = 2; nj < 4; ++nj) {
        acc[mi][nj] = mfma16(af[mi][0], bfr[nj][0], acc[mi][nj]);
        acc[mi][nj] = mfma16(af[mi][1], bfr[nj][1], acc[mi][nj]);
      }
    __builtin_amdgcn_s_setprio(0);

    // ---- phase 2: read A mi{2,3}; stage B(t+2) half1; MFMA mi23 x nj23
#pragma unroll
    for (int mi = 2; mi < 4; ++mi) { af[mi][0] = rdA(mi, 0); af[mi][1] = rdA(mi, 1); }
    if (doStage) stageBh(t + 2, sbuf, 1);
    __builtin_amdgcn_s_setprio(1);
#pragma unroll
    for (int mi = 2; mi < 4; ++mi)
#pragma unroll
      for (int nj = 2; nj < 4; ++nj) {
        acc[mi][nj] = mfma16(af[mi][0], bfr[nj][0], acc[mi][nj]);
        acc[mi][nj] = mfma16(af[mi][1], bfr[nj][1], acc[mi][nj]);
      }
    __builtin_amdgcn_s_setprio(0);

    // ---- phase 3: MFMA mi23 x nj01 (all frags held in regs)
    __builtin_amdgcn_s_setprio(1);
#pragma unroll
    for (int mi = 2; mi < 4; ++mi)
#pragma unroll
      for (int nj = 0; nj < 2; ++nj) {
        acc[mi][nj] = mfma16(af[mi][0], bfr[nj][0], acc[mi][nj]);
        acc[mi][nj] = mfma16(af[mi][1], bfr[nj][1], acc[mi][nj]);
      }
    __builtin_amdgcn_s_setprio(0);

    // ---- K-tile boundary: ensure KT t+1 landed; keep KT t+2 (6 loads) in flight
    if (doStage) asm volatile("s_waitcnt vmcnt(6)" ::: "memory");
    else         asm volatile("s_waitcnt vmcnt(0)" ::: "memory");
    __builtin_amdgcn_s_barrier();
    asm volatile("" ::: "memory");
    buf = (buf == 2) ? 0 : buf + 1;
    sbuf = (sbuf == 2) ? 0 : sbuf + 1;
  }

#pragma unroll
  for (int mi = 0; mi < 4; ++mi) {
#pragma unroll
    for (int nj = 0; nj < 4; ++nj) {
      int row0 = bm * 128 + wm * 64 + mi * 16 + l4 * 4;
      int col  = bn * 256 + wn * 64 + nj * 16 + l15;
#pragma unroll
      for (int r = 0; r < 4; ++r) {
        float v = acc[mi][nj][r];
        if (BF16OUT) ((u16*)Cv)[(size_t)(row0 + r) * N + col] = f2b(v);
        else         ((float*)Cv)[(size_t)(row0 + r) * N + col] = v;
      }
    }
  }
}

// ---------- flash attention: 256 blocks, 8 waves, paired q-tiles, dbuf single-barrier ----------
__global__ __launch_bounds__(512) void k_attn(const u16* __restrict__ qkv,
                                              const u16* __restrict__ vt,
                                              u16* __restrict__ aout) {
  __shared__ __align__(16) u16 Ks[2][64 * 128];  // [kv][d], XOR-swizzled rows
  __shared__ __align__(16) u16 Vs[2][128 * 64];  // V^T [d][kv], XOR-swizzled rows
  __shared__ __align__(16) u16 Ps[8 * 16 * 72];  // per-wave P, stride 72
  const int bid = blockIdx.x;                    // 256 blocks
  const int bh = bid >> 3, pairi = bid & 7;
  const int b = bh >> 4, h = bh & 15;
  const int qtA = pairi, qtB = 15 - pairi;       // paired q-tiles: uniform total work
  const int tid = threadIdx.x, w = tid >> 6, lane = tid & 63;
  const int l15 = lane & 15, l4 = lane >> 4;

  // Q fragments (pre-scaled by 1/sqrt(d) in RoPE), 16 rows per wave per tile
  bf16x8 qfA[4], qfB[4];
  {
    const u16* qpA = qkv + (size_t)(b * LSEQ + qtA * 128 + w * 16 + l15) * NQK + h * HD;
    const u16* qpB = qkv + (size_t)(b * LSEQ + qtB * 128 + w * 16 + l15) * NQK + h * HD;
#pragma unroll
    for (int ks = 0; ks < 4; ++ks) {
      qfA[ks] = *(const bf16x8*)(qpA + ks * 32 + l4 * 8);
      qfB[ks] = *(const bf16x8*)(qpB + ks * 32 + l4 * 8);
    }
  }

  f32x4 accA[8] = {}, accB[8] = {};
  float mA[4], lA[4], mB[4], lB[4];
#pragma unroll
  for (int r = 0; r < 4; ++r) { mA[r] = -1e30f; lA[r] = 0.f; mB[r] = -1e30f; lB[r] = 0.f; }

  const u16* kb  = qkv + (size_t)b * LSEQ * NQK + HIDDEN + h * HD;
  const u16* vtb = vt + (size_t)bh * HD * LSEQ;
  const int ntA = 2 * qtA + 2, ntB = 2 * qtB + 2;

  auto stage = [&](int t, int bf) {
    const int kv0 = t * 64;
    char* Kd = (char*)(&Ks[bf][0]);
    char* Vd = (char*)(&Vs[bf][0]);
#pragma unroll
    for (int p = 0; p < 2; ++p) {
      int cc = p * 512 + tid;
      int row = cc >> 4, sl = cc & 15;
      gload16(kb + (size_t)(kv0 + row) * NQK + ((sl ^ (row & 7)) * 8), Kd + (p * 512 + w * 64) * 16);
    }
#pragma unroll
    for (int p = 0; p < 2; ++p) {
      int cc = p * 512 + tid;
      int d = cc >> 3, sl = cc & 7;
      gload16(vtb + (size_t)d * LSEQ + kv0 + ((sl ^ (d & 7)) * 8), Vd + (p * 512 + w * 64) * 16);
    }
  };

  auto computeTile = [&](const bf16x8 (&qf)[4], f32x4 (&acc_o)[8], float (&mrun)[4],
                         float (&lrun)[4], int qt, int kv0, int cur) {
    const int qbase = qt * 128 + w * 16;
    if (kv0 > qbase + 15) return;                // wave has no valid cols this tile
    const char* KsC = (const char*)(&Ks[cur][0]);
    const char* VsC = (const char*)(&Vs[cur][0]);

    f32x4 accs[4] = {};
    __builtin_amdgcn_s_setprio(1);
#pragma unroll
    for (int ks = 0; ks < 4; ++ks) {
#pragma unroll
      for (int nj = 0; nj < 4; ++nj) {
        int row = nj * 16 + l15;
        int co = (ks * 64 + l4 * 16) ^ ((row & 7) << 4);
        bf16x8 kf = *(const bf16x8*)(KsC + row * 256 + co);
        accs[nj] = mfma16(qf[ks], kf, accs[nj]);
      }
    }
    __builtin_amdgcn_s_setprio(0);

    const int qrow0 = qbase + l4 * 4;
    float pv[4][4], pmax[4];
    if (kv0 + 63 <= qbase) {                     // interior tile: no masking
#pragma unroll
      for (int r = 0; r < 4; ++r) {
        pmax[r] = fmaxf(fmaxf(accs[0][r], accs[1][r]), fmaxf(accs[2][r], accs[3][r]));
#pragma unroll
        for (int nj = 0; nj < 4; ++nj) pv[nj][r] = accs[nj][r];
      }
    } else {
#pragma unroll
      for (int r = 0; r < 4; ++r) {
        float mx = -3e38f;
#pragma unroll
        for (int nj = 0; nj < 4; ++nj) {
          int kvcol = kv0 + nj * 16 + l15;
          float sv = (kvcol <= qrow0 + r) ? accs[nj][r] : -3e38f;
          pv[nj][r] = sv;
          mx = fmaxf(mx, sv);
        }
        pmax[r] = mx;
      }
    }
#pragma unroll
    for (int r = 0; r < 4; ++r) {
      pmax[r] = fmaxf(pmax[r], __shfl_xor(pmax[r], 1));
      pmax[r] = fmaxf(pmax[r], __shfl_xor(pmax[r], 2));
      pmax[r] = fmaxf(pmax[r], __shfl_xor(pmax[r], 4));
      pmax[r] = fmaxf(pmax[r], __shfl_xor(pmax[r], 8));
    }
    // T13 defer-max: rescale only when tile max exceeds running max by >8
    bool need = false;
#pragma unroll
    for (int r = 0; r < 4; ++r) need = need || (pmax[r] > mrun[r] + 8.f);
    if (__any(need)) {
#pragma unroll
      for (int r = 0; r < 4; ++r) {
        float nm = fmaxf(mrun[r], pmax[r]);
        float cf = __expf(mrun[r] - nm);
        mrun[r] = nm;
        lrun[r] *= cf;
#pragma unroll
        for (int df = 0; df < 8; ++df) acc_o[df][r] *= cf;
      }
    }
#pragma unroll
    for (int r = 0; r < 4; ++r) {
      float s = 0.f;
#pragma unroll
      for (int nj = 0; nj < 4; ++nj) {
        float e = __expf(pv[nj][r] - mrun[r]);
        pv[nj][r] = e;
        s += e;
      }
      s += __shfl_xor(s, 1);
      s += __shfl_xor(s, 2);
      s += __shfl_xor(s, 4);
      s += __shfl_xor(s, 8);
      lrun[r] += s;
    }
    // P -> LDS (wave-private rows; no cross-wave barrier needed)
#pragma unroll
    for (int nj = 0; nj < 4; ++nj)
#pragma unroll
      for (int r = 0; r < 4; ++r)
        Ps[(w * 16 + l4 * 4 + r) * 72 + nj * 16 + l15] = f2b(pv[nj][r]);

    bf16x8 pa[2];
#pragma unroll
    for (int ks2 = 0; ks2 < 2; ++ks2)
      pa[ks2] = *(const bf16x8*)(Ps + (w * 16 + l15) * 72 + ks2 * 32 + l4 * 8);
    __builtin_amdgcn_s_setprio(1);
#pragma unroll
    for (int df = 0; df < 8; ++df) {
#pragma unroll
      for (int ks2 = 0; ks2 < 2; ++ks2) {
        int vrow = df * 16 + l15;
        int co = (ks2 * 64 + l4 * 16) ^ ((vrow & 7) << 4);
        bf16x8 bv = *(const bf16x8*)(VsC + vrow * 128 + co);
        acc_o[df] = mfma16(pa[ks2], bv, acc_o[df]);
      }
    }
    __builtin_amdgcn_s_setprio(0);
  };

  stage(0, 0);
  __syncthreads();
  int cur = 0;
  for (int t = 0; t < ntB; ++t) {
    if (t + 1 < ntB) stage(t + 1, cur ^ 1);      // prefetch next tile (other buffer)
    const int kv0 = t * 64;
    if (t < ntA) computeTile(qfA, accA, mA, lA, qtA, kv0, cur);
    computeTile(qfB, accB, mB, lB, qtB, kv0, cur);
    __syncthreads();                             // drains prefetch + guards buffer reuse
    cur ^= 1;
  }

  // epilogue: O /= l, write bf16 [B*L][HIDDEN]
#pragma unroll
  for (int r = 0; r < 4; ++r) {
    float invA = 1.f / lA[r];
    float invB = 1.f / lB[r];
    u16* opA = aout + (size_t)(b * LSEQ + qtA * 128 + w * 16 + l4 * 4 + r) * HIDDEN + h * HD;
    u16* opB = aout + (size_t)(b * LSEQ + qtB * 128 + w * 16 + l4 * 4 + r) * HIDDEN + h * HD;
#pragma unroll
    for (int df = 0; df < 8; ++df) {
      opA[df * 16 + l15] = f2b(accA[df][r] * invA);
      opB[df * 16 + l15] = f2b(accB[df][r] * invB);
    }
  }
}

extern "C" void kernel_launch(void* const* d_in, const int* in_sizes, int n_in,
                              void* d_out, int out_size, void* d_ws, size_t ws_size,
                              hipStream_t stream) {
  const float* hidden = (const float*)d_in[0];
  // d_in[1] = attention_mask: causal, applied analytically in k_attn
  const int*   pos = (const int*)d_in[2];
  const float* Wq = (const float*)d_in[3];
  const float* Wk = (const float*)d_in[4];
  const float* Wv = (const float*)d_in[5];
  const float* Wo = (const float*)d_in[6];
  float* out = (float*)d_out;

  char* ws = (char*)d_ws;
  u16* hbf   = (u16*)ws;                                  // [4096][2048] bf16 (reused as attn_out)
  u16* WT    = (u16*)(ws + 16777216);                     // [6144][2048] bf16 (dead after QKV GEMM)
  u16* vt    = WT;                                        // [32][128][2048] bf16 V^T (aliases WT)
  u16* WoT   = (u16*)(ws + 16777216 + 25165824);          // [2048][2048] bf16
  u16* qkv   = (u16*)(ws + 50331648);                     // [4096][6144] bf16
  float* tab = (float*)(ws + 100663296);                  // [2048][64] {cos,sin}
  u16* aout  = hbf;

  int pstride = (in_sizes[2] == LSEQ) ? 1 : 2;            // int32 vs int64-as-int-pairs

  k_f32_to_bf16<<<8192, 256, 0, stream>>>(hidden, hbf, 2097152);
  dim3 tg(32, 32);
  k_transpose_bf16<<<tg, 256, 0, stream>>>(Wq, WT,                   2048, 2048);
  k_transpose_bf16<<<tg, 256, 0, stream>>>(Wk, WT + 2048 * 2048,     2048, 2048);
  k_transpose_bf16<<<tg, 256, 0, stream>>>(Wv, WT + 2 * 2048 * 2048, 2048, 2048);
  k_transpose_bf16<<<tg, 256, 0, stream>>>(Wo, WoT,                  2048, 2048);
  k_rope_table<<<512, 256, 0, stream>>>(pos, tab, pstride);
  k_gemm2<1><<<dim3(24, 32), 512, 0, stream>>>(hbf, WT, qkv, 4096, 6144, 2048);
  k_transpose_v<<<dim3(32, 2, 32), 256, 0, stream>>>(qkv, vt);
  k_rope_apply<<<16384, 256, 0, stream>>>(qkv, tab);
  k_attn<<<256, 512, 0, stream>>>(qkv, vt, aout);
  k_gemm2<0><<<dim3(8, 32), 512, 0, stream>>>(aout, WoT, out, 4096, 2048, 2048);
}